// Round 4
// baseline (644.774 us; speedup 1.0000x reference)
//
#include <hip/hip_runtime.h>
#include <hip/hip_bf16.h>
#include <math.h>
#include <stdint.h>

#define BATCH   4
#define TSEQ    1024
#define DMODEL  1024
#define NHEAD   16
#define DHEAD   64
#define HFF     4096
#define MROWS   (BATCH * TSEQ)   // 4096

typedef _Float16 f16;
typedef __attribute__((ext_vector_type(2))) _Float16 f16x2;
typedef __attribute__((ext_vector_type(4))) _Float16 f16x4;
typedef __attribute__((ext_vector_type(8))) _Float16 f16x8;
typedef __attribute__((ext_vector_type(4))) float    f32x4;

// ---------------------------------------------------------------------------
// fp32 -> f16 conversion (activations only now)
// ---------------------------------------------------------------------------
__global__ __launch_bounds__(256)
void cvt_f32_f16(const float* __restrict__ in, f16* __restrict__ out, int n)
{
    const int i = (blockIdx.x * 256 + threadIdx.x) * 8;
    if (i < n) {
        const float4 a = *(const float4*)(in + i);
        const float4 b = *(const float4*)(in + i + 4);
        f16x8 o;
        o[0] = (_Float16)a.x; o[1] = (_Float16)a.y; o[2] = (_Float16)a.z; o[3] = (_Float16)a.w;
        o[4] = (_Float16)b.x; o[5] = (_Float16)b.y; o[6] = (_Float16)b.z; o[7] = (_Float16)b.w;
        *(f16x8*)(out + i) = o;
    }
}

// ---------------------------------------------------------------------------
// f16 MFMA GEMM, 128x128 tile, BK=32, 4 waves (2x2), double-buffered LDS.
// A (f16) staged via global_load_lds w16. W read as fp32 DIRECTLY from the
// input weights (4 segment pointers, each covering 1024 N-rows; tiles are
// 128-aligned so a block never straddles a segment), converted f32->f16 in
// registers and ds_write'd into the idle buffer (single barrier per K-step).
// Bias fp32 direct (4 segment pointers). XCD-bijective blockIdx swizzle (T1).
// C[M,N] = A @ W^T + bias (+R) (+relu), f16 out.
// ---------------------------------------------------------------------------
template<bool RES, bool RELU>
__global__ __launch_bounds__(256, 2)
void hgemm(const f16* __restrict__ A,
           const float* __restrict__ w0, const float* __restrict__ w1,
           const float* __restrict__ w2, const float* __restrict__ w3,
           const float* __restrict__ b0, const float* __restrict__ b1,
           const float* __restrict__ b2, const float* __restrict__ b3,
           const f16* __restrict__ Rm, f16* __restrict__ C,
           int M, int N, int K)
{
    constexpr int TM = 128, TN = 128, TK = 32;
    constexpr int NB = 4;       // 4 col-frags per wave (wave covers 64x64)
    constexpr int AISS = 2;     // A stage chunks (128x32 / (256 thr * 8 elem))
    constexpr int BISS = 2;
    __shared__ alignas(16) f16 As[2][TM * TK];
    __shared__ alignas(16) f16 Bs[2][TN * TK];

    const int t = threadIdx.x, ln = t & 63, wv = t >> 6;
    const int wr = wv >> 1, wc = wv & 1;

    // XCD-aware bijective swizzle: XCD k gets a contiguous wid range ->
    // contiguous row-panels share the A panel in that XCD's L2.
    const int gx = gridDim.x, nb = gx * gridDim.y;
    const int d  = blockIdx.y * gx + blockIdx.x;
    const int wid = (d & 7) * (nb >> 3) + (d >> 3);
    const int bx = wid % gx, by = wid / gx;

    const size_t m0 = (size_t)by * TM, n0 = (size_t)bx * TN;

    const float* wseg[4] = {w0, w1, w2, w3};
    const float* bseg[4] = {b0, b1, b2, b3};
    const float* Wg = wseg[n0 >> 10] + ((n0 & 1023) + (t >> 2)) * (size_t)K + (t & 3) * 8;
    const f16*   Ag = A + (m0 + (t >> 2)) * (size_t)K + (t & 3) * 8;

    f32x4 acc[4][NB];
#pragma unroll
    for (int i = 0; i < 4; ++i)
#pragma unroll
        for (int j = 0; j < NB; ++j) acc[i][j] = (f32x4){0.f, 0.f, 0.f, 0.f};

    auto stage_A = [&](int buf, int k0) {
#pragma unroll
        for (int i = 0; i < AISS; ++i)
            __builtin_amdgcn_global_load_lds(
                (const __attribute__((address_space(1))) unsigned int*)(Ag + (size_t)(i * 64) * K + k0),
                (__attribute__((address_space(3))) unsigned int*)(&As[buf][(i * 256 + wv * 64) * 8]),
                16, 0, 0);
    };

    float4 br[BISS][2];
    auto issue_B = [&](int k0) {
#pragma unroll
        for (int i = 0; i < BISS; ++i) {
            br[i][0] = *(const float4*)(Wg + (size_t)(i * 64) * K + k0);
            br[i][1] = *(const float4*)(Wg + (size_t)(i * 64) * K + k0 + 4);
        }
    };
    auto write_B = [&](int buf) {
#pragma unroll
        for (int i = 0; i < BISS; ++i) {
            f16x8 v;
            v[0] = (_Float16)br[i][0].x; v[1] = (_Float16)br[i][0].y;
            v[2] = (_Float16)br[i][0].z; v[3] = (_Float16)br[i][0].w;
            v[4] = (_Float16)br[i][1].x; v[5] = (_Float16)br[i][1].y;
            v[6] = (_Float16)br[i][1].z; v[7] = (_Float16)br[i][1].w;
            *(f16x8*)&Bs[buf][(i * 256 + t) * 8] = v;
        }
    };

    stage_A(0, 0);
    issue_B(0);
    write_B(0);
    __syncthreads();

    int buf = 0;
    for (int k0 = 0; k0 < K; k0 += TK) {
        const int knext = k0 + TK;
        if (knext < K) { stage_A(buf ^ 1, knext); issue_B(knext); }

        f16x8 af[4], bf[NB];
        const f16* Ab = As[buf];
        const f16* Bb = Bs[buf];
#pragma unroll
        for (int i = 0; i < 4; ++i)
            af[i] = *(const f16x8*)(Ab + (wr * 64 + i * 16 + (ln & 15)) * TK + (ln >> 4) * 8);
#pragma unroll
        for (int j = 0; j < NB; ++j)
            bf[j] = *(const f16x8*)(Bb + (wc * 64 + j * 16 + (ln & 15)) * TK + (ln >> 4) * 8);
#pragma unroll
        for (int i = 0; i < 4; ++i)
#pragma unroll
            for (int j = 0; j < NB; ++j)
                acc[i][j] = __builtin_amdgcn_mfma_f32_16x16x32_f16(af[i], bf[j], acc[i][j], 0, 0, 0);

        if (knext < K) write_B(buf ^ 1);   // into idle buffer; published by barrier
        __syncthreads();
        buf ^= 1;
    }

    const int colbase = (int)n0 + wc * 64 + (ln & 15);
    const int rowbase = (int)m0 + wr * 64 + (ln >> 4) * 4;
#pragma unroll
    for (int i = 0; i < 4; ++i) {
#pragma unroll
        for (int j = 0; j < NB; ++j) {
            const int col = colbase + j * 16;
            const float bj = bseg[col >> 10][col & 1023];
#pragma unroll
            for (int r = 0; r < 4; ++r) {
                const int row = rowbase + i * 16 + r;
                float v = acc[i][j][r] + bj;
                if (RES) v += (float)Rm[(size_t)row * N + col];
                if (RELU) v = fmaxf(v, 0.f);
                C[(size_t)row * N + col] = (f16)v;
            }
        }
    }
}

// ---------------------------------------------------------------------------
// MFMA flash attention (validated R3). f16 in/out, fp32 softmax/accum.
// ---------------------------------------------------------------------------
template<bool CAUSAL>
__global__ __launch_bounds__(256, 2)
void attn_mfma(const f16* __restrict__ Qp, int qstr,
               const f16* __restrict__ Kp, int kstr,
               const f16* __restrict__ Vp, int vstr,
               const float* __restrict__ maskp,
               f16* __restrict__ Op)
{
    __shared__ alignas(16) f16 Ks[64 * 64];
    __shared__ alignas(16) f16 Vt[64 * 64];
    __shared__ alignas(16) f16 Ps[4][16 * 64];
    __shared__ alignas(16) float Msk[64];

    const int t = threadIdx.x, l = t & 63, wv = t >> 6;
    const int g = l >> 4, lq = l & 15, a = l & 7;
    const int bh = blockIdx.y, b = bh >> 4, h = bh & 15;
    const int q0 = blockIdx.x * 64;
    const int q0w = q0 + wv * 16;
    const int bT = b * TSEQ;

    f16x8 qf[2];
    {
        const f16* qp = Qp + (size_t)(bT + q0w + lq) * qstr + h * 64 + g * 8;
        qf[0] = *(const f16x8*)(qp);
        qf[1] = *(const f16x8*)(qp + 32);
    }

    f32x4 oacc[4];
#pragma unroll
    for (int i = 0; i < 4; ++i) oacc[i] = (f32x4){0.f, 0.f, 0.f, 0.f};
    float mrun = -1e30f, lrun = 0.f;

    const float* mrow = maskp + b * TSEQ;
    const int kend = CAUSAL ? (q0 + 64) : TSEQ;
    const int qmaxw = q0w + 15;

    f16x8 kr0, kr1, vr0, vr1;
    float mreg = 0.f;
    const int kkey = t >> 3, kd8 = t & 7;

    auto issue_loads = [&](int k0) {
        kr0 = *(const f16x8*)(Kp + (size_t)(bT + k0 + kkey) * kstr + h * 64 + kd8 * 8);
        kr1 = *(const f16x8*)(Kp + (size_t)(bT + k0 + 32 + kkey) * kstr + h * 64 + kd8 * 8);
        vr0 = *(const f16x8*)(Vp + (size_t)(bT + k0 + l) * vstr + h * 64 + wv * 8);
        vr1 = *(const f16x8*)(Vp + (size_t)(bT + k0 + l) * vstr + h * 64 + (4 + wv) * 8);
        if (t < 64) mreg = mrow[k0 + t];
    };
    auto write_stage = [&]() {
        *(f16x8*)&Ks[kkey * 64 + ((kd8 * 8) ^ ((kkey & 7) * 8))] = kr0;
        const int k2 = kkey + 32;
        *(f16x8*)&Ks[k2 * 64 + ((kd8 * 8) ^ ((k2 & 7) * 8))] = kr1;
#pragma unroll
        for (int e = 0; e < 8; ++e) {
            const int d0 = wv * 8 + e;
            const int d1 = (4 + wv) * 8 + e;
            Vt[d0 * 64 + (l ^ (e * 8))] = vr0[e];
            Vt[d1 * 64 + (l ^ (e * 8))] = vr1[e];
        }
        if (t < 64) Msk[t] = mreg;
    };

    issue_loads(0);
    write_stage();
    __syncthreads();

    f16* Pw = Ps[wv];

    for (int k0 = 0; k0 < kend; k0 += 64) {
        const int knext = k0 + 64;
        if (knext < kend) issue_loads(knext);

        if (!CAUSAL || k0 <= qmaxw) {
            f32x4 sacc[4];
#pragma unroll
            for (int kt = 0; kt < 4; ++kt) {
                const int row = kt * 16 + lq;
                const int sw = (row & 7) * 8;
                const f16x8 a0 = *(const f16x8*)&Ks[row * 64 + ((g * 8) ^ sw)];
                const f16x8 a1 = *(const f16x8*)&Ks[row * 64 + (((4 + g) * 8) ^ sw)];
                f32x4 z = (f32x4){0.f, 0.f, 0.f, 0.f};
                z = __builtin_amdgcn_mfma_f32_16x16x32_f16(a0, qf[0], z, 0, 0, 0);
                sacc[kt] = __builtin_amdgcn_mfma_f32_16x16x32_f16(a1, qf[1], z, 0, 0, 0);
            }
            float p[4][4];
            float tmax = -3.0e38f;
#pragma unroll
            for (int kt = 0; kt < 4; ++kt) {
                const float4 mk = *(const float4*)&Msk[kt * 16 + g * 4];
                const float mka[4] = {mk.x, mk.y, mk.z, mk.w};
#pragma unroll
                for (int r = 0; r < 4; ++r) {
                    float s = sacc[kt][r] * (1.f / 32.f) - (1.f - mka[r]) * 3.125e8f;
                    if (CAUSAL) {
                        const int key = k0 + kt * 16 + g * 4 + r;
                        if (key > q0w + lq) s = -3.0e38f;
                    }
                    p[kt][r] = s;
                    tmax = fmaxf(tmax, s);
                }
            }
            tmax = fmaxf(tmax, __shfl_xor(tmax, 16));
            tmax = fmaxf(tmax, __shfl_xor(tmax, 32));
            const float mnew = fmaxf(mrun, tmax);
            const float corr = __expf(mrun - mnew);
            mrun = mnew;
            lrun *= corr;
#pragma unroll
            for (int i = 0; i < 4; ++i) {
                oacc[i][0] *= corr; oacc[i][1] *= corr;
                oacc[i][2] *= corr; oacc[i][3] *= corr;
            }
            float rsum = 0.f;
#pragma unroll
            for (int kt = 0; kt < 4; ++kt)
#pragma unroll
                for (int r = 0; r < 4; ++r) {
                    const float e = __expf(p[kt][r] - mnew);
                    p[kt][r] = e;
                    rsum += e;
                }
            rsum += __shfl_xor(rsum, 16);
            rsum += __shfl_xor(rsum, 32);
            lrun += rsum;
#pragma unroll
            for (int kt = 0; kt < 4; ++kt) {
                f16x4 pv;
                pv[0] = (_Float16)p[kt][0]; pv[1] = (_Float16)p[kt][1];
                pv[2] = (_Float16)p[kt][2]; pv[3] = (_Float16)p[kt][3];
                const int kb = kt * 16 + g * 4;
                *(f16x4*)&Pw[lq * 64 + (kb ^ (a * 8))] = pv;
            }
            const f16x8 pf0 = *(const f16x8*)&Pw[lq * 64 + ((g * 8) ^ (a * 8))];
            const f16x8 pf1 = *(const f16x8*)&Pw[lq * 64 + (((4 + g) * 8) ^ (a * 8))];
#pragma unroll
            for (int dt = 0; dt < 4; ++dt) {
                const int row = dt * 16 + lq;
                const int sw = (row & 7) * 8;
                const f16x8 v0 = *(const f16x8*)&Vt[row * 64 + ((g * 8) ^ sw)];
                const f16x8 v1 = *(const f16x8*)&Vt[row * 64 + (((4 + g) * 8) ^ sw)];
                oacc[dt] = __builtin_amdgcn_mfma_f32_16x16x32_f16(v0, pf0, oacc[dt], 0, 0, 0);
                oacc[dt] = __builtin_amdgcn_mfma_f32_16x16x32_f16(v1, pf1, oacc[dt], 0, 0, 0);
            }
        }

        __syncthreads();
        if (knext < kend) write_stage();
        __syncthreads();
    }

    const float inv = 1.f / lrun;
#pragma unroll
    for (int dt = 0; dt < 4; ++dt) {
        f16x4 ov;
        ov[0] = (_Float16)(oacc[dt][0] * inv); ov[1] = (_Float16)(oacc[dt][1] * inv);
        ov[2] = (_Float16)(oacc[dt][2] * inv); ov[3] = (_Float16)(oacc[dt][3] * inv);
        const int db = dt * 16 + g * 4;
        *(f16x4*)&Pw[lq * 64 + (db ^ (a * 8))] = ov;
    }
#pragma unroll
    for (int i = 0; i < 2; ++i) {
        const int c = i * 64 + l;
        const int row = c >> 3, c8 = c & 7;
        const f16x8 ov = *(const f16x8*)&Pw[row * 64 + ((c8 * 8) ^ ((row & 7) * 8))];
        *(f16x8*)(Op + (size_t)(bT + q0w + row) * DMODEL + h * 64 + c8 * 8) = ov;
    }
}

// ---------------------------------------------------------------------------
// LayerNorm: unbiased var (/(D-1)), eps added to STD. f16 in, f16 or f32 out.
// ---------------------------------------------------------------------------
__inline__ __device__ float block_sum256(float v, float* sm)
{
#pragma unroll
    for (int off = 32; off > 0; off >>= 1) v += __shfl_down(v, off, 64);
    const int lane = threadIdx.x & 63, w = threadIdx.x >> 6;
    if (lane == 0) sm[w] = v;
    __syncthreads();
    const float r = sm[0] + sm[1] + sm[2] + sm[3];
    __syncthreads();
    return r;
}

template<bool F32OUT>
__global__ __launch_bounds__(256)
void ln_kernel(const f16* __restrict__ X, const float* __restrict__ g,
               const float* __restrict__ be, void* __restrict__ Yv)
{
    __shared__ float sm[4];
    const int row = blockIdx.x;
    const size_t base = (size_t)row * DMODEL + threadIdx.x * 4;
    const f16x4 xv = *(const f16x4*)(X + base);
    float x[4] = {(float)xv[0], (float)xv[1], (float)xv[2], (float)xv[3]};

    float s = x[0] + x[1] + x[2] + x[3];
    s = block_sum256(s, sm);
    const float mean = s * (1.0f / (float)DMODEL);

    float dx[4] = {x[0] - mean, x[1] - mean, x[2] - mean, x[3] - mean};
    float s2 = dx[0] * dx[0] + dx[1] * dx[1] + dx[2] * dx[2] + dx[3] * dx[3];
    s2 = block_sum256(s2, sm);
    const float rs = 1.0f / (sqrtf(s2 * (1.0f / (float)(DMODEL - 1))) + 1e-6f);

    const float4 gv = *(const float4*)(g + threadIdx.x * 4);
    const float4 bv = *(const float4*)(be + threadIdx.x * 4);
    const float y0 = gv.x * dx[0] * rs + bv.x;
    const float y1 = gv.y * dx[1] * rs + bv.y;
    const float y2 = gv.z * dx[2] * rs + bv.z;
    const float y3 = gv.w * dx[3] * rs + bv.w;
    if (F32OUT) {
        float4 y = {y0, y1, y2, y3};
        *(float4*)((float*)Yv + base) = y;
    } else {
        f16x4 y; y[0] = (_Float16)y0; y[1] = (_Float16)y1; y[2] = (_Float16)y2; y[3] = (_Float16)y3;
        *(f16x4*)((f16*)Yv + base) = y;
    }
}

// ---------------------------------------------------------------------------
extern "C" void kernel_launch(void* const* d_in, const int* in_sizes, int n_in,
                              void* d_out, int out_size, void* d_ws, size_t ws_size,
                              hipStream_t stream)
{
    (void)in_sizes; (void)n_in; (void)out_size; (void)ws_size;

    const float* x        = (const float*)d_in[0];
    const float* enc      = (const float*)d_in[1];
    const float* mask_src = (const float*)d_in[2];
    const float* mask_trg = (const float*)d_in[3];
    const float* sa_wq = (const float*)d_in[4];  const float* sa_bq = (const float*)d_in[5];
    const float* sa_wk = (const float*)d_in[6];  const float* sa_bk = (const float*)d_in[7];
    const float* sa_wv = (const float*)d_in[8];  const float* sa_bv = (const float*)d_in[9];
    const float* sa_wo = (const float*)d_in[10]; const float* sa_bo = (const float*)d_in[11];
    const float* sa_g  = (const float*)d_in[12]; const float* sa_b  = (const float*)d_in[13];
    const float* ca_wq = (const float*)d_in[14]; const float* ca_bq = (const float*)d_in[15];
    const float* ca_wk = (const float*)d_in[16]; const float* ca_bk = (const float*)d_in[17];
    const float* ca_wv = (const float*)d_in[18]; const float* ca_bv = (const float*)d_in[19];
    const float* ca_wo = (const float*)d_in[20]; const float* ca_bo = (const float*)d_in[21];
    const float* ca_g  = (const float*)d_in[22]; const float* ca_b  = (const float*)d_in[23];
    const float* ff_w1 = (const float*)d_in[24]; const float* ff_b1 = (const float*)d_in[25];
    const float* ff_w2 = (const float*)d_in[26]; const float* ff_b2 = (const float*)d_in[27];
    const float* ff_g  = (const float*)d_in[28]; const float* ff_b  = (const float*)d_in[29];

    f16* ws = (f16*)d_ws;
    const size_t MEG = 1024 * 1024;
    f16* G  = ws + 4 * MEG;     // QKV (12M) / Q2 (4M) + KV2 (8M) / FF1-out (16M)
    f16* S0 = ws + 20 * MEG;    // x (f16)
    f16* S1 = ws + 24 * MEG;    // enc (f16)
    f16* S2 = ws + 28 * MEG;    // attn out
    f16* S3 = ws + 32 * MEG;    // pre-LN
    f16* S4 = ws + 36 * MEG;    // H1
    f16* S5 = ws + 40 * MEG;    // H2

    const int NACT = MROWS * DMODEL;   // 4M

    dim3 blk(256);
    const int cvAct = NACT / 2048;
    dim3 gQKV(3072 / 128, MROWS / 128);   // 768 blocks
    dim3 gN1 (1024 / 128, MROWS / 128);   // 256 blocks
    dim3 gKV (2048 / 128, MROWS / 128);   // 512 blocks
    dim3 gFF1(4096 / 128, MROWS / 128);   // 1024 blocks
    dim3 agrid(TSEQ / 64, BATCH * NHEAD);

    // ---- self-attention (causal) ----
    cvt_f32_f16<<<cvAct, blk, 0, stream>>>(x, S0, NACT);
    cvt_f32_f16<<<cvAct, blk, 0, stream>>>(enc, S1, NACT);
    hgemm<false, false><<<gQKV, blk, 0, stream>>>(S0,
        sa_wq, sa_wk, sa_wv, sa_wv, sa_bq, sa_bk, sa_bv, sa_bv,
        nullptr, G, MROWS, 3072, DMODEL);
    attn_mfma<true><<<agrid, blk, 0, stream>>>(G, 3072, G + 1024, 3072, G + 2048, 3072, mask_trg, S2);
    hgemm<true, false><<<gN1, blk, 0, stream>>>(S2,
        sa_wo, sa_wo, sa_wo, sa_wo, sa_bo, sa_bo, sa_bo, sa_bo,
        S0, S3, MROWS, DMODEL, DMODEL);
    ln_kernel<false><<<MROWS, blk, 0, stream>>>(S3, sa_g, sa_b, S4);   // H1 = S4

    // ---- cross-attention ----
    hgemm<false, false><<<gN1, blk, 0, stream>>>(S4,
        ca_wq, ca_wq, ca_wq, ca_wq, ca_bq, ca_bq, ca_bq, ca_bq,
        nullptr, G, MROWS, DMODEL, DMODEL);                             // Q2
    hgemm<false, false><<<gKV, blk, 0, stream>>>(S1,
        ca_wk, ca_wv, ca_wv, ca_wv, ca_bk, ca_bv, ca_bv, ca_bv,
        nullptr, G + 4 * MEG, MROWS, 2048, DMODEL);                     // K2V2
    attn_mfma<false><<<agrid, blk, 0, stream>>>(G, 1024, G + 4 * MEG, 2048, G + 4 * MEG + 1024, 2048, mask_src, S2);
    hgemm<true, false><<<gN1, blk, 0, stream>>>(S2,
        ca_wo, ca_wo, ca_wo, ca_wo, ca_bo, ca_bo, ca_bo, ca_bo,
        S4, S3, MROWS, DMODEL, DMODEL);
    ln_kernel<false><<<MROWS, blk, 0, stream>>>(S3, ca_g, ca_b, S5);   // H2 = S5

    // ---- feedforward ----
    hgemm<false, true><<<gFF1, blk, 0, stream>>>(S5,
        ff_w1, ff_w1 + 1024 * (size_t)DMODEL, ff_w1 + 2048 * (size_t)DMODEL, ff_w1 + 3072 * (size_t)DMODEL,
        ff_b1, ff_b1 + 1024, ff_b1 + 2048, ff_b1 + 3072,
        nullptr, G, MROWS, HFF, DMODEL);
    hgemm<true, false><<<gN1, blk, 0, stream>>>(G,
        ff_w2, ff_w2, ff_w2, ff_w2, ff_b2, ff_b2, ff_b2, ff_b2,
        S5, S3, MROWS, DMODEL, HFF);
    ln_kernel<true><<<MROWS, blk, 0, stream>>>(S3, ff_g, ff_b, d_out);
}

// Round 5
// 581.478 us; speedup vs baseline: 1.1089x; 1.1089x over previous
//
#include <hip/hip_runtime.h>
#include <hip/hip_bf16.h>
#include <math.h>
#include <stdint.h>

#define BATCH   4
#define TSEQ    1024
#define DMODEL  1024
#define NHEAD   16
#define DHEAD   64
#define HFF     4096
#define MROWS   (BATCH * TSEQ)   // 4096

typedef _Float16 f16;
typedef __attribute__((ext_vector_type(2))) _Float16 f16x2;
typedef __attribute__((ext_vector_type(4))) _Float16 f16x4;
typedef __attribute__((ext_vector_type(8))) _Float16 f16x8;
typedef __attribute__((ext_vector_type(4))) float    f32x4;

// ---------------------------------------------------------------------------
// fp32 -> f16 conversion (vectorized, 8 elems/thread)
// ---------------------------------------------------------------------------
__global__ __launch_bounds__(256)
void cvt_f32_f16(const float* __restrict__ in, f16* __restrict__ out, int n)
{
    const int i = (blockIdx.x * 256 + threadIdx.x) * 8;
    if (i < n) {
        const float4 a = *(const float4*)(in + i);
        const float4 b = *(const float4*)(in + i + 4);
        f16x8 o;
        o[0] = (_Float16)a.x; o[1] = (_Float16)a.y; o[2] = (_Float16)a.z; o[3] = (_Float16)a.w;
        o[4] = (_Float16)b.x; o[5] = (_Float16)b.y; o[6] = (_Float16)b.z; o[7] = (_Float16)b.w;
        *(f16x8*)(out + i) = o;
    }
}

// ---------------------------------------------------------------------------
// f16 MFMA GEMM (R3-validated structure): C = A @ W^T + bias (+R) (+relu).
// Tile 128 x TN, BK=32, 256 thr = 4 waves (2x2), double-buffered LDS,
// global_load_lds w16 for both operands, f16 weights (pre-converted).
// NEW (R5): XCD-bijective blockIdx swizzle — each XCD gets a contiguous wid
// range (bx-fastest), so its A row-panels + the W panel stay L2-resident.
// ---------------------------------------------------------------------------
template<int TN, bool RES, bool RELU>
__global__ __launch_bounds__(256, 2)
void hgemm(const f16* __restrict__ A, const f16* __restrict__ Wt,
           const float* __restrict__ bias, const f16* __restrict__ Rm,
           f16* __restrict__ C, int M, int N, int K)
{
    constexpr int TM = 128, TK = 32;
    constexpr int NB = TN / 32;
    constexpr int AISS = (TM * TK) / (256 * 8);
    constexpr int BISS = (TN * TK) / (256 * 8);
    __shared__ alignas(16) f16 As[2][TM * TK];
    __shared__ alignas(16) f16 Bs[2][TN * TK];

    const int t = threadIdx.x, ln = t & 63, wv = t >> 6;
    const int wr = wv >> 1, wc = wv & 1;

    // XCD swizzle: dispatch round-robins linear id d over 8 XCDs; remap so
    // XCD (d&7) owns contiguous wid => sweeps bx for a few row-panels.
    const int gx = gridDim.x;
    const int nbk = gx * gridDim.y;          // all grids are %8 == 0
    const int d  = blockIdx.y * gx + blockIdx.x;
    const int wid = (d & 7) * (nbk >> 3) + (d >> 3);
    const int bx = wid % gx, by = wid / gx;

    const size_t m0 = (size_t)by * TM, n0 = (size_t)bx * TN;

    f32x4 acc[4][NB];
#pragma unroll
    for (int i = 0; i < 4; ++i)
#pragma unroll
        for (int j = 0; j < NB; ++j) acc[i][j] = (f32x4){0.f, 0.f, 0.f, 0.f};

    const f16* Ag = A + (m0 + (t >> 2)) * (size_t)K + (t & 3) * 8;
    const f16* Bg = Wt + (n0 + (t >> 2)) * (size_t)K + (t & 3) * 8;

    auto stage = [&](int buf, int k0) {
#pragma unroll
        for (int i = 0; i < AISS; ++i)
            __builtin_amdgcn_global_load_lds(
                (const __attribute__((address_space(1))) unsigned int*)(Ag + (size_t)(i * 64) * K + k0),
                (__attribute__((address_space(3))) unsigned int*)(&As[buf][(i * 256 + wv * 64) * 8]),
                16, 0, 0);
#pragma unroll
        for (int i = 0; i < BISS; ++i)
            __builtin_amdgcn_global_load_lds(
                (const __attribute__((address_space(1))) unsigned int*)(Bg + (size_t)(i * 64) * K + k0),
                (__attribute__((address_space(3))) unsigned int*)(&Bs[buf][(i * 256 + wv * 64) * 8]),
                16, 0, 0);
    };

    stage(0, 0);
    __syncthreads();
    int buf = 0;
    for (int k0 = 0; k0 < K; k0 += TK) {
        if (k0 + TK < K) stage(buf ^ 1, k0 + TK);
        f16x8 af[4], bf[NB];
        const f16* Ab = As[buf];
        const f16* Bb = Bs[buf];
#pragma unroll
        for (int i = 0; i < 4; ++i)
            af[i] = *(const f16x8*)(Ab + (wr * 64 + i * 16 + (ln & 15)) * TK + (ln >> 4) * 8);
#pragma unroll
        for (int j = 0; j < NB; ++j)
            bf[j] = *(const f16x8*)(Bb + (wc * (TN / 2) + j * 16 + (ln & 15)) * TK + (ln >> 4) * 8);
#pragma unroll
        for (int i = 0; i < 4; ++i)
#pragma unroll
            for (int j = 0; j < NB; ++j)
                acc[i][j] = __builtin_amdgcn_mfma_f32_16x16x32_f16(af[i], bf[j], acc[i][j], 0, 0, 0);
        __syncthreads();
        buf ^= 1;
    }

    const int colbase = (int)n0 + wc * (TN / 2) + (ln & 15);
    const int rowbase = (int)m0 + wr * 64 + (ln >> 4) * 4;
#pragma unroll
    for (int i = 0; i < 4; ++i) {
#pragma unroll
        for (int j = 0; j < NB; ++j) {
            const int col = colbase + j * 16;
            const float bj = bias[col];
#pragma unroll
            for (int r = 0; r < 4; ++r) {
                const int row = rowbase + i * 16 + r;
                float v = acc[i][j][r] + bj;
                if (RES) v += (float)Rm[(size_t)row * N + col];
                if (RELU) v = fmaxf(v, 0.f);
                C[(size_t)row * N + col] = (f16)v;
            }
        }
    }
}

// ---------------------------------------------------------------------------
// MFMA flash attention (validated R3). f16 in/out, fp32 softmax/accum.
// ---------------------------------------------------------------------------
template<bool CAUSAL>
__global__ __launch_bounds__(256, 2)
void attn_mfma(const f16* __restrict__ Qp, int qstr,
               const f16* __restrict__ Kp, int kstr,
               const f16* __restrict__ Vp, int vstr,
               const float* __restrict__ maskp,
               f16* __restrict__ Op)
{
    __shared__ alignas(16) f16 Ks[64 * 64];
    __shared__ alignas(16) f16 Vt[64 * 64];
    __shared__ alignas(16) f16 Ps[4][16 * 64];
    __shared__ alignas(16) float Msk[64];

    const int t = threadIdx.x, l = t & 63, wv = t >> 6;
    const int g = l >> 4, lq = l & 15, a = l & 7;
    const int bh = blockIdx.y, b = bh >> 4, h = bh & 15;
    const int q0 = blockIdx.x * 64;
    const int q0w = q0 + wv * 16;
    const int bT = b * TSEQ;

    f16x8 qf[2];
    {
        const f16* qp = Qp + (size_t)(bT + q0w + lq) * qstr + h * 64 + g * 8;
        qf[0] = *(const f16x8*)(qp);
        qf[1] = *(const f16x8*)(qp + 32);
    }

    f32x4 oacc[4];
#pragma unroll
    for (int i = 0; i < 4; ++i) oacc[i] = (f32x4){0.f, 0.f, 0.f, 0.f};
    float mrun = -1e30f, lrun = 0.f;

    const float* mrow = maskp + b * TSEQ;
    const int kend = CAUSAL ? (q0 + 64) : TSEQ;
    const int qmaxw = q0w + 15;

    f16x8 kr0, kr1, vr0, vr1;
    float mreg = 0.f;
    const int kkey = t >> 3, kd8 = t & 7;

    auto issue_loads = [&](int k0) {
        kr0 = *(const f16x8*)(Kp + (size_t)(bT + k0 + kkey) * kstr + h * 64 + kd8 * 8);
        kr1 = *(const f16x8*)(Kp + (size_t)(bT + k0 + 32 + kkey) * kstr + h * 64 + kd8 * 8);
        vr0 = *(const f16x8*)(Vp + (size_t)(bT + k0 + l) * vstr + h * 64 + wv * 8);
        vr1 = *(const f16x8*)(Vp + (size_t)(bT + k0 + l) * vstr + h * 64 + (4 + wv) * 8);
        if (t < 64) mreg = mrow[k0 + t];
    };
    auto write_stage = [&]() {
        *(f16x8*)&Ks[kkey * 64 + ((kd8 * 8) ^ ((kkey & 7) * 8))] = kr0;
        const int k2 = kkey + 32;
        *(f16x8*)&Ks[k2 * 64 + ((kd8 * 8) ^ ((k2 & 7) * 8))] = kr1;
#pragma unroll
        for (int e = 0; e < 8; ++e) {
            const int d0 = wv * 8 + e;
            const int d1 = (4 + wv) * 8 + e;
            Vt[d0 * 64 + (l ^ (e * 8))] = vr0[e];
            Vt[d1 * 64 + (l ^ (e * 8))] = vr1[e];
        }
        if (t < 64) Msk[t] = mreg;
    };

    issue_loads(0);
    write_stage();
    __syncthreads();

    f16* Pw = Ps[wv];

    for (int k0 = 0; k0 < kend; k0 += 64) {
        const int knext = k0 + 64;
        if (knext < kend) issue_loads(knext);

        if (!CAUSAL || k0 <= qmaxw) {
            f32x4 sacc[4];
#pragma unroll
            for (int kt = 0; kt < 4; ++kt) {
                const int row = kt * 16 + lq;
                const int sw = (row & 7) * 8;
                const f16x8 a0 = *(const f16x8*)&Ks[row * 64 + ((g * 8) ^ sw)];
                const f16x8 a1 = *(const f16x8*)&Ks[row * 64 + (((4 + g) * 8) ^ sw)];
                f32x4 z = (f32x4){0.f, 0.f, 0.f, 0.f};
                z = __builtin_amdgcn_mfma_f32_16x16x32_f16(a0, qf[0], z, 0, 0, 0);
                sacc[kt] = __builtin_amdgcn_mfma_f32_16x16x32_f16(a1, qf[1], z, 0, 0, 0);
            }
            float p[4][4];
            float tmax = -3.0e38f;
#pragma unroll
            for (int kt = 0; kt < 4; ++kt) {
                const float4 mk = *(const float4*)&Msk[kt * 16 + g * 4];
                const float mka[4] = {mk.x, mk.y, mk.z, mk.w};
#pragma unroll
                for (int r = 0; r < 4; ++r) {
                    float s = sacc[kt][r] * (1.f / 32.f) - (1.f - mka[r]) * 3.125e8f;
                    if (CAUSAL) {
                        const int key = k0 + kt * 16 + g * 4 + r;
                        if (key > q0w + lq) s = -3.0e38f;
                    }
                    p[kt][r] = s;
                    tmax = fmaxf(tmax, s);
                }
            }
            tmax = fmaxf(tmax, __shfl_xor(tmax, 16));
            tmax = fmaxf(tmax, __shfl_xor(tmax, 32));
            const float mnew = fmaxf(mrun, tmax);
            const float corr = __expf(mrun - mnew);
            mrun = mnew;
            lrun *= corr;
#pragma unroll
            for (int i = 0; i < 4; ++i) {
                oacc[i][0] *= corr; oacc[i][1] *= corr;
                oacc[i][2] *= corr; oacc[i][3] *= corr;
            }
            float rsum = 0.f;
#pragma unroll
            for (int kt = 0; kt < 4; ++kt)
#pragma unroll
                for (int r = 0; r < 4; ++r) {
                    const float e = __expf(p[kt][r] - mnew);
                    p[kt][r] = e;
                    rsum += e;
                }
            rsum += __shfl_xor(rsum, 16);
            rsum += __shfl_xor(rsum, 32);
            lrun += rsum;
#pragma unroll
            for (int kt = 0; kt < 4; ++kt) {
                f16x4 pv;
                pv[0] = (_Float16)p[kt][0]; pv[1] = (_Float16)p[kt][1];
                pv[2] = (_Float16)p[kt][2]; pv[3] = (_Float16)p[kt][3];
                const int kb = kt * 16 + g * 4;
                *(f16x4*)&Pw[lq * 64 + (kb ^ (a * 8))] = pv;
            }
            const f16x8 pf0 = *(const f16x8*)&Pw[lq * 64 + ((g * 8) ^ (a * 8))];
            const f16x8 pf1 = *(const f16x8*)&Pw[lq * 64 + (((4 + g) * 8) ^ (a * 8))];
#pragma unroll
            for (int dt = 0; dt < 4; ++dt) {
                const int row = dt * 16 + lq;
                const int sw = (row & 7) * 8;
                const f16x8 v0 = *(const f16x8*)&Vt[row * 64 + ((g * 8) ^ sw)];
                const f16x8 v1 = *(const f16x8*)&Vt[row * 64 + (((4 + g) * 8) ^ sw)];
                oacc[dt] = __builtin_amdgcn_mfma_f32_16x16x32_f16(v0, pf0, oacc[dt], 0, 0, 0);
                oacc[dt] = __builtin_amdgcn_mfma_f32_16x16x32_f16(v1, pf1, oacc[dt], 0, 0, 0);
            }
        }

        __syncthreads();
        if (knext < kend) write_stage();
        __syncthreads();
    }

    const float inv = 1.f / lrun;
#pragma unroll
    for (int dt = 0; dt < 4; ++dt) {
        f16x4 ov;
        ov[0] = (_Float16)(oacc[dt][0] * inv); ov[1] = (_Float16)(oacc[dt][1] * inv);
        ov[2] = (_Float16)(oacc[dt][2] * inv); ov[3] = (_Float16)(oacc[dt][3] * inv);
        const int db = dt * 16 + g * 4;
        *(f16x4*)&Pw[lq * 64 + (db ^ (a * 8))] = ov;
    }
#pragma unroll
    for (int i = 0; i < 2; ++i) {
        const int c = i * 64 + l;
        const int row = c >> 3, c8 = c & 7;
        const f16x8 ov = *(const f16x8*)&Pw[row * 64 + ((c8 * 8) ^ ((row & 7) * 8))];
        *(f16x8*)(Op + (size_t)(bT + q0w + row) * DMODEL + h * 64 + c8 * 8) = ov;
    }
}

// ---------------------------------------------------------------------------
// LayerNorm: unbiased var (/(D-1)), eps added to STD. f16 in, f16 or f32 out.
// ---------------------------------------------------------------------------
__inline__ __device__ float block_sum256(float v, float* sm)
{
#pragma unroll
    for (int off = 32; off > 0; off >>= 1) v += __shfl_down(v, off, 64);
    const int lane = threadIdx.x & 63, w = threadIdx.x >> 6;
    if (lane == 0) sm[w] = v;
    __syncthreads();
    const float r = sm[0] + sm[1] + sm[2] + sm[3];
    __syncthreads();
    return r;
}

template<bool F32OUT>
__global__ __launch_bounds__(256)
void ln_kernel(const f16* __restrict__ X, const float* __restrict__ g,
               const float* __restrict__ be, void* __restrict__ Yv)
{
    __shared__ float sm[4];
    const int row = blockIdx.x;
    const size_t base = (size_t)row * DMODEL + threadIdx.x * 4;
    const f16x4 xv = *(const f16x4*)(X + base);
    float x[4] = {(float)xv[0], (float)xv[1], (float)xv[2], (float)xv[3]};

    float s = x[0] + x[1] + x[2] + x[3];
    s = block_sum256(s, sm);
    const float mean = s * (1.0f / (float)DMODEL);

    float dx[4] = {x[0] - mean, x[1] - mean, x[2] - mean, x[3] - mean};
    float s2 = dx[0] * dx[0] + dx[1] * dx[1] + dx[2] * dx[2] + dx[3] * dx[3];
    s2 = block_sum256(s2, sm);
    const float rs = 1.0f / (sqrtf(s2 * (1.0f / (float)(DMODEL - 1))) + 1e-6f);

    const float4 gv = *(const float4*)(g + threadIdx.x * 4);
    const float4 bv = *(const float4*)(be + threadIdx.x * 4);
    const float y0 = gv.x * dx[0] * rs + bv.x;
    const float y1 = gv.y * dx[1] * rs + bv.y;
    const float y2 = gv.z * dx[2] * rs + bv.z;
    const float y3 = gv.w * dx[3] * rs + bv.w;
    if (F32OUT) {
        float4 y = {y0, y1, y2, y3};
        *(float4*)((float*)Yv + base) = y;
    } else {
        f16x4 y; y[0] = (_Float16)y0; y[1] = (_Float16)y1; y[2] = (_Float16)y2; y[3] = (_Float16)y3;
        *(f16x4*)((f16*)Yv + base) = y;
    }
}

// ---------------------------------------------------------------------------
extern "C" void kernel_launch(void* const* d_in, const int* in_sizes, int n_in,
                              void* d_out, int out_size, void* d_ws, size_t ws_size,
                              hipStream_t stream)
{
    (void)in_sizes; (void)n_in; (void)out_size; (void)ws_size;

    const float* x        = (const float*)d_in[0];
    const float* enc      = (const float*)d_in[1];
    const float* mask_src = (const float*)d_in[2];
    const float* mask_trg = (const float*)d_in[3];
    const float* sa_wq = (const float*)d_in[4];  const float* sa_bq = (const float*)d_in[5];
    const float* sa_wk = (const float*)d_in[6];  const float* sa_bk = (const float*)d_in[7];
    const float* sa_wv = (const float*)d_in[8];  const float* sa_bv = (const float*)d_in[9];
    const float* sa_wo = (const float*)d_in[10]; const float* sa_bo = (const float*)d_in[11];
    const float* sa_g  = (const float*)d_in[12]; const float* sa_b  = (const float*)d_in[13];
    const float* ca_wq = (const float*)d_in[14]; const float* ca_bq = (const float*)d_in[15];
    const float* ca_wk = (const float*)d_in[16]; const float* ca_bk = (const float*)d_in[17];
    const float* ca_wv = (const float*)d_in[18]; const float* ca_bv = (const float*)d_in[19];
    const float* ca_wo = (const float*)d_in[20]; const float* ca_bo = (const float*)d_in[21];
    const float* ca_g  = (const float*)d_in[22]; const float* ca_b  = (const float*)d_in[23];
    const float* ff_w1 = (const float*)d_in[24]; const float* ff_b1 = (const float*)d_in[25];
    const float* ff_w2 = (const float*)d_in[26]; const float* ff_b2 = (const float*)d_in[27];
    const float* ff_g  = (const float*)d_in[28]; const float* ff_b  = (const float*)d_in[29];

    f16* ws = (f16*)d_ws;
    const size_t MEG = 1024 * 1024;
    f16* Wh = ws;
    f16* G  = ws + 4 * MEG;
    f16* S0 = ws + 20 * MEG;
    f16* S1 = ws + 24 * MEG;
    f16* S2 = ws + 28 * MEG;
    f16* S3 = ws + 32 * MEG;
    f16* S4 = ws + 36 * MEG;
    f16* S5 = ws + 40 * MEG;
    float* Bias = (float*)((char*)d_ws + 88 * MEG);

    const int NACT = MROWS * DMODEL;   // 4M
    const int NW   = DMODEL * DMODEL;  // 1M

    dim3 blk(256);
    const int cvAct = NACT / 2048, cvW = NW / 2048, cvFF = (4 * NW) / 2048;
    dim3 gQKV(3072 / 128, MROWS / 128);   // 768 blocks
    dim3 gN64(DMODEL / 64, MROWS / 128);  // 512 blocks
    dim3 gKV(2048 / 128, MROWS / 128);    // 512 blocks
    dim3 gFF1(HFF / 128, MROWS / 128);    // 1024 blocks
    dim3 agrid(TSEQ / 64, BATCH * NHEAD);

    // ---- self-attention (causal) ----
    cvt_f32_f16<<<cvAct, blk, 0, stream>>>(x, S0, NACT);
    cvt_f32_f16<<<cvAct, blk, 0, stream>>>(enc, S1, NACT);
    cvt_f32_f16<<<cvW, blk, 0, stream>>>(sa_wq, Wh, NW);
    cvt_f32_f16<<<cvW, blk, 0, stream>>>(sa_wk, Wh + 1 * MEG, NW);
    cvt_f32_f16<<<cvW, blk, 0, stream>>>(sa_wv, Wh + 2 * MEG, NW);
    hipMemcpyAsync(Bias + 0,    sa_bq, 4096, hipMemcpyDeviceToDevice, stream);
    hipMemcpyAsync(Bias + 1024, sa_bk, 4096, hipMemcpyDeviceToDevice, stream);
    hipMemcpyAsync(Bias + 2048, sa_bv, 4096, hipMemcpyDeviceToDevice, stream);
    hgemm<128, false, false><<<gQKV, blk, 0, stream>>>(S0, Wh, Bias, nullptr, G, MROWS, 3072, DMODEL);
    attn_mfma<true><<<agrid, blk, 0, stream>>>(G, 3072, G + 1024, 3072, G + 2048, 3072, mask_trg, S2);
    cvt_f32_f16<<<cvW, blk, 0, stream>>>(sa_wo, Wh, NW);
    hipMemcpyAsync(Bias, sa_bo, 4096, hipMemcpyDeviceToDevice, stream);
    hgemm<64, true, false><<<gN64, blk, 0, stream>>>(S2, Wh, Bias, S0, S3, MROWS, DMODEL, DMODEL);
    ln_kernel<false><<<MROWS, blk, 0, stream>>>(S3, sa_g, sa_b, S4);   // H1 = S4

    // ---- cross-attention ----
    cvt_f32_f16<<<cvW, blk, 0, stream>>>(ca_wq, Wh, NW);
    hipMemcpyAsync(Bias, ca_bq, 4096, hipMemcpyDeviceToDevice, stream);
    hgemm<64, false, false><<<gN64, blk, 0, stream>>>(S4, Wh, Bias, nullptr, G, MROWS, DMODEL, DMODEL);  // Q2
    cvt_f32_f16<<<cvW, blk, 0, stream>>>(ca_wk, Wh, NW);
    cvt_f32_f16<<<cvW, blk, 0, stream>>>(ca_wv, Wh + 1 * MEG, NW);
    hipMemcpyAsync(Bias + 0,    ca_bk, 4096, hipMemcpyDeviceToDevice, stream);
    hipMemcpyAsync(Bias + 1024, ca_bv, 4096, hipMemcpyDeviceToDevice, stream);
    hgemm<128, false, false><<<gKV, blk, 0, stream>>>(S1, Wh, Bias, nullptr, G + 4 * MEG, MROWS, 2048, DMODEL); // K2V2
    attn_mfma<false><<<agrid, blk, 0, stream>>>(G, 1024, G + 4 * MEG, 2048, G + 4 * MEG + 1024, 2048, mask_src, S2);
    cvt_f32_f16<<<cvW, blk, 0, stream>>>(ca_wo, Wh, NW);
    hipMemcpyAsync(Bias, ca_bo, 4096, hipMemcpyDeviceToDevice, stream);
    hgemm<64, true, false><<<gN64, blk, 0, stream>>>(S2, Wh, Bias, S4, S3, MROWS, DMODEL, DMODEL);
    ln_kernel<false><<<MROWS, blk, 0, stream>>>(S3, ca_g, ca_b, S5);   // H2 = S5

    // ---- feedforward ----
    cvt_f32_f16<<<cvFF, blk, 0, stream>>>(ff_w1, Wh, 4 * NW);
    hipMemcpyAsync(Bias, ff_b1, 16384, hipMemcpyDeviceToDevice, stream);
    hgemm<128, false, true><<<gFF1, blk, 0, stream>>>(S5, Wh, Bias, nullptr, G, MROWS, HFF, DMODEL);
    cvt_f32_f16<<<cvFF, blk, 0, stream>>>(ff_w2, Wh, 4 * NW);
    hipMemcpyAsync(Bias, ff_b2, 4096, hipMemcpyDeviceToDevice, stream);
    hgemm<64, true, false><<<gN64, blk, 0, stream>>>(G, Wh, Bias, S5, S3, MROWS, DMODEL, HFF);
    ln_kernel<true><<<MROWS, blk, 0, stream>>>(S3, ff_g, ff_b, d_out);
}

// Round 8
// 516.655 us; speedup vs baseline: 1.2480x; 1.1255x over previous
//
#include <hip/hip_runtime.h>
#include <hip/hip_bf16.h>
#include <math.h>
#include <stdint.h>

#define BATCH   4
#define TSEQ    1024
#define DMODEL  1024
#define NHEAD   16
#define DHEAD   64
#define HFF     4096
#define MROWS   (BATCH * TSEQ)   // 4096

typedef _Float16 f16;
typedef __attribute__((ext_vector_type(4))) _Float16 f16x4;
typedef __attribute__((ext_vector_type(8))) _Float16 f16x8;
typedef __attribute__((ext_vector_type(4))) float    f32x4;

#define MEG (1u << 20)

// ---------------------------------------------------------------------------
// prep_w: one kernel converts all fp32 weights + x + enc to f16.
// 12 segments, static block->segment map. 2048 elems/block.
// ---------------------------------------------------------------------------
struct WSrcs { const float* p[12]; };

__global__ __launch_bounds__(256)
void prep_w(WSrcs s, f16* __restrict__ wb)
{
    const int blk = blockIdx.x;
    int seg, off;
    if      (blk <  4096) { seg = blk >> 9; off = blk & 511;  }
    else if (blk <  6144) { seg = 8;  off = blk - 4096; }
    else if (blk <  8192) { seg = 9;  off = blk - 6144; }
    else if (blk < 10240) { seg = 10; off = blk - 8192; }
    else                  { seg = 11; off = blk - 10240; }
    const unsigned dsto[12] = {0, 1*MEG, 2*MEG, 3*MEG, 4*MEG, 5*MEG, 6*MEG, 7*MEG,
                               8*MEG, 12*MEG, 32*MEG, 36*MEG};
    const int i = off * 2048 + threadIdx.x * 8;
    const float4 a = *(const float4*)(s.p[seg] + i);
    const float4 b = *(const float4*)(s.p[seg] + i + 4);
    f16x8 o;
    o[0] = (_Float16)a.x; o[1] = (_Float16)a.y; o[2] = (_Float16)a.z; o[3] = (_Float16)a.w;
    o[4] = (_Float16)b.x; o[5] = (_Float16)b.y; o[6] = (_Float16)b.z; o[7] = (_Float16)b.w;
    *(f16x8*)(wb + dsto[seg] + i) = o;
}

// prep_b: gathers the 10 fp32 bias vectors into one contiguous fp32 buffer.
struct BSrcs { const float* p[10]; };

__global__ __launch_bounds__(256)
void prep_b(BSrcs s, float* __restrict__ bias)
{
    const int blk = blockIdx.x;
    int seg, off;
    if      (blk <  8) { seg = blk; off = 0; }
    else if (blk < 12) { seg = 8;   off = blk - 8; }
    else               { seg = 9;   off = 0; }
    const unsigned dsto[10] = {0, 1024, 2048, 3072, 4096, 5120, 6144, 7168, 8192, 12288};
    const int i = off * 1024 + threadIdx.x * 4;
    const float4 v = *(const float4*)(s.p[seg] + i);
    *(float4*)(bias + dsto[seg] + i) = v;
}

// ---------------------------------------------------------------------------
// f16 MFMA GEMM: C[M,N] = A[M,K] @ W[N,K]^T + bias (+R) (+relu), f16 out.
// TM=128 x TN tile, BK=TK, 4 waves (2x2), double-buffered LDS via
// global_load_lds w16. LDS XOR-swizzle (T2) applied through pre-swizzled
// GLOBAL source chunks + swizzled fragment reads (rule #21): chunk c of row r
// lives at linear chunk (c ^ (r & (TK/8-1))). TK=64 -> 2-way (free).
// XCD-bijective blockIdx swizzle (T1, validated R5: FETCH 139->53MB).
// A row stride = lda (allows reading attn output embedded in QKV buffer).
// ---------------------------------------------------------------------------
template<int TN, int TK, bool RES, bool RELU>
__global__ __launch_bounds__(256, 2)
void hgemm(const f16* __restrict__ A, int lda,
           const f16* __restrict__ Wt, const float* __restrict__ bias,
           const f16* __restrict__ Rm, f16* __restrict__ C,
           int M, int N, int K)
{
    constexpr int TM = 128;
    constexpr int NB = TN / 32;       // 16-col frags per wave
    constexpr int NK = TK / 32;       // k-subtiles per phase
    constexpr int CH = TK / 8;        // 8-elem chunks per row
    constexpr int RPI = 256 / CH;     // rows staged per iteration
    constexpr int AISS = TM / RPI, BISS = TN / RPI;
    constexpr int KM = CH - 1;        // swizzle key mask
    __shared__ alignas(16) f16 As[2][TM * TK];
    __shared__ alignas(16) f16 Bs[2][TN * TK];

    const int t = threadIdx.x, ln = t & 63, wv = t >> 6;
    const int wr = wv >> 1, wc = wv & 1;

    // T1 swizzle (all grids %8 == 0)
    const int gx = gridDim.x;
    const int nbk = gx * gridDim.y;
    const int dd = blockIdx.y * gx + blockIdx.x;
    const int wid = (dd & 7) * (nbk >> 3) + (dd >> 3);
    const int bx = wid % gx, by = wid / gx;
    const size_t m0 = (size_t)by * TM, n0 = (size_t)bx * TN;

    f32x4 acc[4][NB];
#pragma unroll
    for (int i = 0; i < 4; ++i)
#pragma unroll
        for (int j = 0; j < NB; ++j) acc[i][j] = (f32x4){0.f, 0.f, 0.f, 0.f};

    const int srow = t / CH;
    const int scol = ((t % CH) ^ (srow & KM)) * 8;   // pre-swizzled source chunk
    const f16* Ag = A + (m0 + srow) * (size_t)lda + scol;
    const f16* Bg = Wt + (n0 + srow) * (size_t)K + scol;

    auto stage = [&](int buf, int k0) {
#pragma unroll
        for (int i = 0; i < AISS; ++i)
            __builtin_amdgcn_global_load_lds(
                (const __attribute__((address_space(1))) unsigned int*)(Ag + (size_t)(i * RPI) * lda + k0),
                (__attribute__((address_space(3))) unsigned int*)(&As[buf][i * RPI * TK + t * 8]),
                16, 0, 0);
#pragma unroll
        for (int i = 0; i < BISS; ++i)
            __builtin_amdgcn_global_load_lds(
                (const __attribute__((address_space(1))) unsigned int*)(Bg + (size_t)(i * RPI) * K + k0),
                (__attribute__((address_space(3))) unsigned int*)(&Bs[buf][i * RPI * TK + t * 8]),
                16, 0, 0);
    };

    stage(0, 0);
    __syncthreads();
    int buf = 0;
    for (int k0 = 0; k0 < K; k0 += TK) {
        if (k0 + TK < K) stage(buf ^ 1, k0 + TK);

        f16x8 af[NK][4], bf[NK][NB];
        const f16* Ab = As[buf];
        const f16* Bb = Bs[buf];
#pragma unroll
        for (int kk = 0; kk < NK; ++kk) {
            const int c = kk * 4 + (ln >> 4);
#pragma unroll
            for (int i = 0; i < 4; ++i) {
                const int row = wr * 64 + i * 16 + (ln & 15);
                af[kk][i] = *(const f16x8*)(Ab + row * TK + ((c ^ (row & KM)) * 8));
            }
#pragma unroll
            for (int j = 0; j < NB; ++j) {
                const int row = wc * (TN / 2) + j * 16 + (ln & 15);
                bf[kk][j] = *(const f16x8*)(Bb + row * TK + ((c ^ (row & KM)) * 8));
            }
        }
#pragma unroll
        for (int kk = 0; kk < NK; ++kk)
#pragma unroll
            for (int i = 0; i < 4; ++i)
#pragma unroll
                for (int j = 0; j < NB; ++j)
                    acc[i][j] = __builtin_amdgcn_mfma_f32_16x16x32_f16(af[kk][i], bf[kk][j], acc[i][j], 0, 0, 0);
        __syncthreads();
        buf ^= 1;
    }

    const int colbase = (int)n0 + wc * (TN / 2) + (ln & 15);
    const int rowbase = (int)m0 + wr * 64 + (ln >> 4) * 4;
#pragma unroll
    for (int i = 0; i < 4; ++i) {
#pragma unroll
        for (int j = 0; j < NB; ++j) {
            const int col = colbase + j * 16;
            const float bj = bias[col];
#pragma unroll
            for (int r = 0; r < 4; ++r) {
                const int row = rowbase + i * 16 + r;
                float v = acc[i][j][r] + bj;
                if (RES) v += (float)Rm[(size_t)row * N + col];
                if (RELU) v = fmaxf(v, 0.f);
                C[(size_t)row * N + col] = (f16)v;
            }
        }
    }
}

// ---------------------------------------------------------------------------
// MFMA flash attention (validated R3). f16 in/out, fp32 softmax/accum.
// Output stride param: writes in-place over its own Q columns (race-free:
// each block writes only the Q fragment rows/cols that it alone reads).
// ---------------------------------------------------------------------------
template<bool CAUSAL>
__global__ __launch_bounds__(256, 2)
void attn_mfma(const f16* __restrict__ Qp, int qstr,
               const f16* __restrict__ Kp, int kstr,
               const f16* __restrict__ Vp, int vstr,
               const float* __restrict__ maskp,
               f16* __restrict__ Op, int ostr)
{
    __shared__ alignas(16) f16 Ks[64 * 64];
    __shared__ alignas(16) f16 Vt[64 * 64];
    __shared__ alignas(16) f16 Ps[4][16 * 64];
    __shared__ alignas(16) float Msk[64];

    const int t = threadIdx.x, l = t & 63, wv = t >> 6;
    const int g = l >> 4, lq = l & 15, a = l & 7;
    const int bh = blockIdx.y, b = bh >> 4, h = bh & 15;
    const int q0 = blockIdx.x * 64;
    const int q0w = q0 + wv * 16;
    const int bT = b * TSEQ;

    f16x8 qf[2];
    {
        const f16* qp = Qp + (size_t)(bT + q0w + lq) * qstr + h * 64 + g * 8;
        qf[0] = *(const f16x8*)(qp);
        qf[1] = *(const f16x8*)(qp + 32);
    }

    f32x4 oacc[4];
#pragma unroll
    for (int i = 0; i < 4; ++i) oacc[i] = (f32x4){0.f, 0.f, 0.f, 0.f};
    float mrun = -1e30f, lrun = 0.f;

    const float* mrow = maskp + b * TSEQ;
    const int kend = CAUSAL ? (q0 + 64) : TSEQ;
    const int qmaxw = q0w + 15;

    f16x8 kr0, kr1, vr0, vr1;
    float mreg = 0.f;
    const int kkey = t >> 3, kd8 = t & 7;

    auto issue_loads = [&](int k0) {
        kr0 = *(const f16x8*)(Kp + (size_t)(bT + k0 + kkey) * kstr + h * 64 + kd8 * 8);
        kr1 = *(const f16x8*)(Kp + (size_t)(bT + k0 + 32 + kkey) * kstr + h * 64 + kd8 * 8);
        vr0 = *(const f16x8*)(Vp + (size_t)(bT + k0 + l) * vstr + h * 64 + wv * 8);
        vr1 = *(const f16x8*)(Vp + (size_t)(bT + k0 + l) * vstr + h * 64 + (4 + wv) * 8);
        if (t < 64) mreg = mrow[k0 + t];
    };
    auto write_stage = [&]() {
        *(f16x8*)&Ks[kkey * 64 + ((kd8 * 8) ^ ((kkey & 7) * 8))] = kr0;
        const int k2 = kkey + 32;
        *(f16x8*)&Ks[k2 * 64 + ((kd8 * 8) ^ ((k2 & 7) * 8))] = kr1;
#pragma unroll
        for (int e = 0; e < 8; ++e) {
            const int d0 = wv * 8 + e;
            const int d1 = (4 + wv) * 8 + e;
            Vt[d0 * 64 + (l ^ (e * 8))] = vr0[e];
            Vt[d1 * 64 + (l ^ (e * 8))] = vr1[e];
        }
        if (t < 64) Msk[t] = mreg;
    };

    issue_loads(0);
    write_stage();
    __syncthreads();

    f16* Pw = Ps[wv];

    for (int k0 = 0; k0 < kend; k0 += 64) {
        const int knext = k0 + 64;
        if (knext < kend) issue_loads(knext);

        if (!CAUSAL || k0 <= qmaxw) {
            f32x4 sacc[4];
#pragma unroll
            for (int kt = 0; kt < 4; ++kt) {
                const int row = kt * 16 + lq;
                const int sw = (row & 7) * 8;
                const f16x8 a0 = *(const f16x8*)&Ks[row * 64 + ((g * 8) ^ sw)];
                const f16x8 a1 = *(const f16x8*)&Ks[row * 64 + (((4 + g) * 8) ^ sw)];
                f32x4 z = (f32x4){0.f, 0.f, 0.f, 0.f};
                z = __builtin_amdgcn_mfma_f32_16x16x32_f16(a0, qf[0], z, 0, 0, 0);
                sacc[kt] = __builtin_amdgcn_mfma_f32_16x16x32_f16(a1, qf[1], z, 0, 0, 0);
            }
            float p[4][4];
            float tmax = -3.0e38f;
#pragma unroll
            for (int kt = 0; kt < 4; ++kt) {
                const float4 mk = *(const float4*)&Msk[kt * 16 + g * 4];
                const float mka[4] = {mk.x, mk.y, mk.z, mk.w};
#pragma unroll
                for (int r = 0; r < 4; ++r) {
                    float s = sacc[kt][r] * (1.f / 32.f) - (1.f - mka[r]) * 3.125e8f;
                    if (CAUSAL) {
                        const int key = k0 + kt * 16 + g * 4 + r;
                        if (key > q0w + lq) s = -3.0e38f;
                    }
                    p[kt][r] = s;
                    tmax = fmaxf(tmax, s);
                }
            }
            tmax = fmaxf(tmax, __shfl_xor(tmax, 16));
            tmax = fmaxf(tmax, __shfl_xor(tmax, 32));
            const float mnew = fmaxf(mrun, tmax);
            const float corr = __expf(mrun - mnew);
            mrun = mnew;
            lrun *= corr;
#pragma unroll
            for (int i = 0; i < 4; ++i) {
                oacc[i][0] *= corr; oacc[i][1] *= corr;
                oacc[i][2] *= corr; oacc[i][3] *= corr;
            }
            float rsum = 0.f;
#pragma unroll
            for (int kt = 0; kt < 4; ++kt)
#pragma unroll
                for (int r = 0; r < 4; ++r) {
                    const float e = __expf(p[kt][r] - mnew);
                    p[kt][r] = e;
                    rsum += e;
                }
            rsum += __shfl_xor(rsum, 16);
            rsum += __shfl_xor(rsum, 32);
            lrun += rsum;
#pragma unroll
            for (int kt = 0; kt < 4; ++kt) {
                f16x4 pv;
                pv[0] = (_Float16)p[kt][0]; pv[1] = (_Float16)p[kt][1];
                pv[2] = (_Float16)p[kt][2]; pv[3] = (_Float16)p[kt][3];
                const int kb = kt * 16 + g * 4;
                *(f16x4*)&Pw[lq * 64 + (kb ^ (a * 8))] = pv;
            }
            const f16x8 pf0 = *(const f16x8*)&Pw[lq * 64 + ((g * 8) ^ (a * 8))];
            const f16x8 pf1 = *(const f16x8*)&Pw[lq * 64 + (((4 + g) * 8) ^ (a * 8))];
#pragma unroll
            for (int dt = 0; dt < 4; ++dt) {
                const int row = dt * 16 + lq;
                const int sw = (row & 7) * 8;
                const f16x8 v0 = *(const f16x8*)&Vt[row * 64 + ((g * 8) ^ sw)];
                const f16x8 v1 = *(const f16x8*)&Vt[row * 64 + (((4 + g) * 8) ^ sw)];
                oacc[dt] = __builtin_amdgcn_mfma_f32_16x16x32_f16(v0, pf0, oacc[dt], 0, 0, 0);
                oacc[dt] = __builtin_amdgcn_mfma_f32_16x16x32_f16(v1, pf1, oacc[dt], 0, 0, 0);
            }
        }

        __syncthreads();
        if (knext < kend) write_stage();
        __syncthreads();
    }

    const float inv = 1.f / lrun;
#pragma unroll
    for (int dt = 0; dt < 4; ++dt) {
        f16x4 ov;
        ov[0] = (_Float16)(oacc[dt][0] * inv); ov[1] = (_Float16)(oacc[dt][1] * inv);
        ov[2] = (_Float16)(oacc[dt][2] * inv); ov[3] = (_Float16)(oacc[dt][3] * inv);
        const int db = dt * 16 + g * 4;
        *(f16x4*)&Pw[lq * 64 + (db ^ (a * 8))] = ov;
    }
#pragma unroll
    for (int i = 0; i < 2; ++i) {
        const int c = i * 64 + l;
        const int row = c >> 3, c8 = c & 7;
        const f16x8 ov = *(const f16x8*)&Pw[row * 64 + ((c8 * 8) ^ ((row & 7) * 8))];
        *(f16x8*)(Op + (size_t)(bT + q0w + row) * ostr + h * 64 + c8 * 8) = ov;
    }
}

// ---------------------------------------------------------------------------
// LayerNorm: unbiased var (/(D-1)), eps added to STD. f16 in, f16 or f32 out.
// ---------------------------------------------------------------------------
__inline__ __device__ float block_sum256(float v, float* sm)
{
#pragma unroll
    for (int off = 32; off > 0; off >>= 1) v += __shfl_down(v, off, 64);
    const int lane = threadIdx.x & 63, w = threadIdx.x >> 6;
    if (lane == 0) sm[w] = v;
    __syncthreads();
    const float r = sm[0] + sm[1] + sm[2] + sm[3];
    __syncthreads();
    return r;
}

template<bool F32OUT>
__global__ __launch_bounds__(256)
void ln_kernel(const f16* __restrict__ X, const float* __restrict__ g,
               const float* __restrict__ be, void* __restrict__ Yv)
{
    __shared__ float sm[4];
    const int row = blockIdx.x;
    const size_t base = (size_t)row * DMODEL + threadIdx.x * 4;
    const f16x4 xv = *(const f16x4*)(X + base);
    float x[4] = {(float)xv[0], (float)xv[1], (float)xv[2], (float)xv[3]};

    float s = x[0] + x[1] + x[2] + x[3];
    s = block_sum256(s, sm);
    const float mean = s * (1.0f / (float)DMODEL);

    float dx[4] = {x[0] - mean, x[1] - mean, x[2] - mean, x[3] - mean};
    float s2 = dx[0] * dx[0] + dx[1] * dx[1] + dx[2] * dx[2] + dx[3] * dx[3];
    s2 = block_sum256(s2, sm);
    const float rs = 1.0f / (sqrtf(s2 * (1.0f / (float)(DMODEL - 1))) + 1e-6f);

    const float4 gv = *(const float4*)(g + threadIdx.x * 4);
    const float4 bv = *(const float4*)(be + threadIdx.x * 4);
    const float y0 = gv.x * dx[0] * rs + bv.x;
    const float y1 = gv.y * dx[1] * rs + bv.y;
    const float y2 = gv.z * dx[2] * rs + bv.z;
    const float y3 = gv.w * dx[3] * rs + bv.w;
    if (F32OUT) {
        float4 y = {y0, y1, y2, y3};
        *(float4*)((float*)Yv + base) = y;
    } else {
        f16x4 y; y[0] = (_Float16)y0; y[1] = (_Float16)y1; y[2] = (_Float16)y2; y[3] = (_Float16)y3;
        *(f16x4*)((f16*)Yv + base) = y;
    }
}

// ---------------------------------------------------------------------------
extern "C" void kernel_launch(void* const* d_in, const int* in_sizes, int n_in,
                              void* d_out, int out_size, void* d_ws, size_t ws_size,
                              hipStream_t stream)
{
    (void)in_sizes; (void)n_in; (void)out_size; (void)ws_size;

    const float* x        = (const float*)d_in[0];
    const float* enc      = (const float*)d_in[1];
    const float* mask_src = (const float*)d_in[2];
    const float* mask_trg = (const float*)d_in[3];
    const float* sa_wq = (const float*)d_in[4];  const float* sa_bq = (const float*)d_in[5];
    const float* sa_wk = (const float*)d_in[6];  const float* sa_bk = (const float*)d_in[7];
    const float* sa_wv = (const float*)d_in[8];  const float* sa_bv = (const float*)d_in[9];
    const float* sa_wo = (const float*)d_in[10]; const float* sa_bo = (const float*)d_in[11];
    const float* sa_g  = (const float*)d_in[12]; const float* sa_b  = (const float*)d_in[13];
    const float* ca_wq = (const float*)d_in[14]; const float* ca_bq = (const float*)d_in[15];
    const float* ca_wk = (const float*)d_in[16]; const float* ca_bk = (const float*)d_in[17];
    const float* ca_wv = (const float*)d_in[18]; const float* ca_bv = (const float*)d_in[19];
    const float* ca_wo = (const float*)d_in[20]; const float* ca_bo = (const float*)d_in[21];
    const float* ca_g  = (const float*)d_in[22]; const float* ca_b  = (const float*)d_in[23];
    const float* ff_w1 = (const float*)d_in[24]; const float* ff_b1 = (const float*)d_in[25];
    const float* ff_w2 = (const float*)d_in[26]; const float* ff_b2 = (const float*)d_in[27];
    const float* ff_g  = (const float*)d_in[28]; const float* ff_b  = (const float*)d_in[29];

    // ---- workspace layout (total 88.05 MB; <= 96 MB known-good) ----
    // Bias fp32 [0, 53248B) | WB f16 16M | G f16 16M | S0 4M | S1 4M | S4 4M
    float* Bias = (float*)d_ws;
    f16* WB = (f16*)d_ws + 26624;
    f16* G  = WB + 16 * (size_t)MEG;    // QKV / Q2+KV2 / FF1-out; preLN at +12M
    f16* S0 = WB + 32 * (size_t)MEG;    // x_f16, later preLN3
    f16* S1 = WB + 36 * (size_t)MEG;    // enc_f16
    f16* S4 = WB + 40 * (size_t)MEG;    // H1, later H2
    f16* PreLN = G + 12 * (size_t)MEG;

    dim3 blk(256);
    dim3 gQKV(3072 / 128, MROWS / 128);   // 768 blocks
    dim3 gN64(1024 / 64,  MROWS / 128);   // 512 blocks (TN=64)
    dim3 gKV (2048 / 128, MROWS / 128);   // 512 blocks
    dim3 gFF1(4096 / 128, MROWS / 128);   // 1024 blocks
    dim3 agrid(TSEQ / 64, BATCH * NHEAD);

    // ---- prep: all weights + activations f16, all biases gathered ----
    WSrcs wsrc = {{sa_wq, sa_wk, sa_wv, sa_wo, ca_wq, ca_wk, ca_wv, ca_wo,
                   ff_w1, ff_w2, x, enc}};
    prep_w<<<12288, blk, 0, stream>>>(wsrc, WB);
    BSrcs bsrc = {{sa_bq, sa_bk, sa_bv, sa_bo, ca_bq, ca_bk, ca_bv, ca_bo,
                   ff_b1, ff_b2}};
    prep_b<<<13, blk, 0, stream>>>(bsrc, Bias);

    // ---- self-attention (causal) ----
    hgemm<128, 32, false, false><<<gQKV, blk, 0, stream>>>(
        S0, DMODEL, WB, Bias, nullptr, G, MROWS, 3072, DMODEL);
    attn_mfma<true><<<agrid, blk, 0, stream>>>(
        G, 3072, G + 1024, 3072, G + 2048, 3072, mask_trg, G, 3072);
    hgemm<64, 64, true, false><<<gN64, blk, 0, stream>>>(
        G, 3072, WB + 3 * (size_t)MEG, Bias + 3072, S0, PreLN, MROWS, DMODEL, DMODEL);
    ln_kernel<false><<<MROWS, blk, 0, stream>>>(PreLN, sa_g, sa_b, S4);   // H1

    // ---- cross-attention ----
    hgemm<64, 64, false, false><<<gN64, blk, 0, stream>>>(
        S4, DMODEL, WB + 4 * (size_t)MEG, Bias + 4096, nullptr, G, MROWS, DMODEL, DMODEL);  // Q2
    hgemm<128, 32, false, false><<<gKV, blk, 0, stream>>>(
        S1, DMODEL, WB + 5 * (size_t)MEG, Bias + 5120, nullptr, G + 4 * (size_t)MEG,
        MROWS, 2048, DMODEL);                                                                // K2V2
    attn_mfma<false><<<agrid, blk, 0, stream>>>(
        G, 1024, G + 4 * (size_t)MEG, 2048, G + 4 * (size_t)MEG + 1024, 2048, mask_src, G, 1024);
    hgemm<64, 64, true, false><<<gN64, blk, 0, stream>>>(
        G, 1024, WB + 7 * (size_t)MEG, Bias + 7168, S4, PreLN, MROWS, DMODEL, DMODEL);
    ln_kernel<false><<<MROWS, blk, 0, stream>>>(PreLN, ca_g, ca_b, S4);   // H2 (H1 dead)

    // ---- feedforward ----
    hgemm<128, 32, false, true><<<gFF1, blk, 0, stream>>>(
        S4, DMODEL, WB + 8 * (size_t)MEG, Bias + 8192, nullptr, G, MROWS, HFF, DMODEL);
    hgemm<64, 64, true, false><<<gN64, blk, 0, stream>>>(
        G, HFF, WB + 12 * (size_t)MEG, Bias + 12288, S4, S0, MROWS, DMODEL, HFF);
    ln_kernel<true><<<MROWS, blk, 0, stream>>>(S0, ff_g, ff_b, d_out);
}